// Round 3
// baseline (356.407 us; speedup 1.0000x reference)
//
#include <hip/hip_runtime.h>

// SNN forward, round 9. Round-8 counters: bin_hh at 83us, FETCH 81MB,
// 1.09TB/s, VALU 21% -- latency-bound, not BW. Cause: per-iteration
// pre-load -> mask test -> CONDITIONAL gather -> ballot chain serializes
// ~16 HBM-latency rounds per wave. Fix: phase-batched loop (all pre loads,
// then all tests, then all gathers issued back-to-back, then compaction)
// -> ~2 latency rounds, same active-only traffic. Also: uint4 mask stage,
// extra/cursor zeroing folded into make_masks (memset dispatch deleted),
// NCOPY back to 20 (round-8's 250-block accum left half the CUs idle;
// CAP 204800->196608 keeps ws within the round-6-proven footprint),
// motor scatter reads the L2-resident mask directly (no 50KB LDS stage).

#define N_SENS 10000
#define N_HID  400000
#define N_MOT  1000

#define CHUNK_LOG 14
#define CHUNK     (1 << CHUNK_LOG)      // 16384 floats = 64 KB LDS chunk
#define NBUCKET   25                    // ceil(400000 / 16384)
#define CAP       196608                // pairs/bucket (expect ~175K max)
#define NCOPY     20                    // accum blocks per bucket (500 total)

#define SENS_MW   320                   // sens mask words (u32) = 10240 bits
#define HID_MW    12512                 // hid mask words (u32) = 400384 bits

#define BUF_SH    4096                  // = 1024*EPT_SH -> cannot overflow
#define BUF_HH    2048                  // ~5x expected actives (~410)
#define EPT_SH    4
#define EPT_HH    8

#define NB_HM     128

// --- masks + zero extra/cursors (replaces a memset dispatch) -------------
__global__ void make_masks(const float* __restrict__ sens_in,
                           const float* __restrict__ sens_mem,
                           const float* __restrict__ hid_prev,
                           uint2* __restrict__ smask,
                           uint2* __restrict__ hmask,
                           float* __restrict__ extra,
                           int* __restrict__ cursors, int nb_sens) {
    bool pred = false;
    int i;
    uint2* dst;
    int maxw;
    if ((int)blockIdx.x < nb_sens) {
        if (blockIdx.x == 0 && threadIdx.x < 32) cursors[threadIdx.x] = 0;
        i = blockIdx.x * blockDim.x + threadIdx.x;
        if (i < N_SENS) pred = (0.9f * sens_mem[i] + 5.0f * sens_in[i]) > 1.0f;
        dst = smask; maxw = SENS_MW / 2;
    } else {
        i = (blockIdx.x - nb_sens) * blockDim.x + threadIdx.x;
        if (i < N_HID) { pred = (hid_prev[i] != 0.0f); extra[i] = 0.0f; }
        dst = hmask; maxw = HID_MW / 2;
    }
    unsigned long long b = __ballot(pred);
    if ((threadIdx.x & 63) == 0) {
        int w = i >> 6;
        if (w < maxw) dst[w] = make_uint2((unsigned)b, (unsigned)(b >> 32));
    }
}

// --- single-pass bin, phase-batched for MLP ------------------------------
template <int MW, int BUFCAP, int EPT>
__global__ __launch_bounds__(1024, 8)
void bin_gather(const int* __restrict__ pre, const int* __restrict__ post,
                const float* __restrict__ w, const unsigned* __restrict__ gmask,
                int n_e, float scale,
                uint2* __restrict__ pairs, int* __restrict__ gcursor,
                float* __restrict__ extra) {
    __shared__ unsigned sm[MW];
    __shared__ uint2 buf[BUFCAP];
    __shared__ int h[4][32];
    __shared__ int gb[32];
    __shared__ int lcur[32];
    __shared__ int total;

    const int tid = threadIdx.x;
    const int lane = tid & 63;
    for (int i = tid; i < MW / 4; i += 1024)
        ((uint4*)sm)[i] = ((const uint4*)gmask)[i];
    if (tid < 128) ((int*)h)[tid] = 0;
    if (tid == 0) total = 0;
    __syncthreads();

    const int base = blockIdx.x * (1024 * EPT) + tid;

    // phase 1: all pre loads in flight
    int pr[EPT];
    #pragma unroll
    for (int j = 0; j < EPT; ++j) {
        int e = base + j * 1024;
        pr[j] = (e < n_e) ? pre[e] : -1;
    }
    // phase 2: mask tests (LDS)
    bool act[EPT];
    #pragma unroll
    for (int j = 0; j < EPT; ++j)
        act[j] = (pr[j] >= 0) && ((sm[pr[j] >> 5] >> (pr[j] & 31)) & 1u);
    // phase 3: all active gathers in flight (exec-masked, active-only traffic)
    unsigned p[EPT]; float wv[EPT];
    #pragma unroll
    for (int j = 0; j < EPT; ++j) {
        p[j] = 0; wv[j] = 0.0f;
        if (act[j]) {
            int e = base + j * 1024;
            p[j] = (unsigned)post[e];
            wv[j] = scale * w[e];
        }
    }
    // phase 4: ballot-compact into LDS pair buffer
    #pragma unroll
    for (int j = 0; j < EPT; ++j) {
        unsigned long long m = __ballot(act[j]);
        if (!m) continue;
        int rank = __popcll(m & ((1ull << lane) - 1ull));
        int bse = 0;
        if (lane == 0) bse = atomicAdd(&total, __popcll(m));
        bse = __shfl(bse, 0);
        if (act[j]) {
            int k = bse + rank;
            if (k < BUFCAP) buf[k] = make_uint2(p[j], __float_as_uint(wv[j]));
            else atomicAdd(&extra[p[j]], wv[j]);   // ~never taken
        }
    }
    __syncthreads();
    int tot = total; if (tot > BUFCAP) tot = BUFCAP;

    // in-LDS histogram (4-way replicated counters)
    int rep = (tid >> 6) & 3;
    for (int k = tid; k < tot; k += 1024)
        atomicAdd(&h[rep][buf[k].x >> CHUNK_LOG], 1);
    __syncthreads();
    if (tid < NBUCKET) {
        int hb = h[0][tid] + h[1][tid] + h[2][tid] + h[3][tid];
        gb[tid] = hb ? atomicAdd(&gcursor[tid], hb) : 0;
        lcur[tid] = 0;
    }
    __syncthreads();

    // flush: bucket-grouped global writes
    for (int k = tid; k < tot; k += 1024) {
        uint2 u = buf[k];
        int b = u.x >> CHUNK_LOG;
        int s = atomicAdd(&lcur[b], 1);
        int pos = gb[b] + s;
        if (pos < CAP)
            pairs[(size_t)b * CAP + pos] =
                make_uint2(u.x & (CHUNK - 1), u.y);
        else
            atomicAdd(&extra[u.x], __uint_as_float(u.y));  // ~never taken
    }
}

// --- Phase B: LDS ds_add accumulation per (bucket, copy) -----------------
__global__ __launch_bounds__(1024, 8)
void accum_bucket(const uint2* __restrict__ pairs,
                  const int* __restrict__ cursors,
                  float* __restrict__ partials) {
    int bucket = blockIdx.x / NCOPY;
    int copy   = blockIdx.x % NCOPY;
    __shared__ float acc[CHUNK];
    for (int i = threadIdx.x; i < CHUNK; i += blockDim.x) acc[i] = 0.0f;
    __syncthreads();

    int count = cursors[bucket];
    if (count > CAP) count = CAP;
    int begin = (int)((long long)count * copy / NCOPY);
    int end   = (int)((long long)count * (copy + 1) / NCOPY);
    const uint2* src = pairs + (size_t)bucket * CAP;
    for (int i = begin + threadIdx.x; i < end; i += blockDim.x) {
        uint2 u = src[i];
        atomicAdd(&acc[u.x], __uint_as_float(u.y));           // LDS atomic
    }
    __syncthreads();
    float* dst = partials + ((size_t)bucket * NCOPY + copy) * CHUNK;
    for (int i = threadIdx.x; i < CHUNK; i += blockDim.x) dst[i] = acc[i];
}

// --- hidden LIF fused with partial merge (+overflow); emits bitmask ------
__global__ void reduce_lif_hidden_mask(const float* __restrict__ partials,
                                       const float* __restrict__ extra,
                                       const float* __restrict__ mem,
                                       uint2* __restrict__ mask) {
    int i = blockIdx.x * blockDim.x + threadIdx.x;
    bool pred = false;
    if (i < N_HID) {
        int b = i >> CHUNK_LOG, local = i & (CHUNK - 1);
        const float* p = partials + (size_t)b * NCOPY * CHUNK + local;
        float sum = extra[i];
        #pragma unroll
        for (int c = 0; c < NCOPY; ++c) sum += p[(size_t)c * CHUNK];
        pred = (0.9f * mem[i] + 5.0f * sum) > 1.0f;
    }
    unsigned long long bal = __ballot(pred);
    if ((threadIdx.x & 63) == 0) {
        int w = i >> 6;
        if (w < HID_MW / 2)
            mask[w] = make_uint2((unsigned)bal, (unsigned)(bal >> 32));
    }
}

// --- motor: LDS accumulator, mask read direct from L2 (50KB resident) ----
__global__ __launch_bounds__(512, 8)
void scatter_motor_mask(const int* __restrict__ pre,
                        const int* __restrict__ post,
                        const float* __restrict__ w,
                        const unsigned* __restrict__ gmask,
                        float* __restrict__ partials, int n_edges) {
    __shared__ float acc[N_MOT];
    for (int j = threadIdx.x; j < N_MOT; j += blockDim.x) acc[j] = 0.0f;
    __syncthreads();
    for (int e = blockIdx.x * blockDim.x + threadIdx.x; e < n_edges;
         e += gridDim.x * blockDim.x) {
        int pr = pre[e];
        if ((gmask[pr >> 5] >> (pr & 31)) & 1u)
            atomicAdd(&acc[post[e]], w[e]);
    }
    __syncthreads();
    float* out = partials + (size_t)blockIdx.x * N_MOT;
    for (int j = threadIdx.x; j < N_MOT; j += blockDim.x) out[j] = acc[j];
}

__global__ void reduce_lif_motor(const float* __restrict__ partials, int nb,
                                 const float* __restrict__ mem,
                                 float* __restrict__ out) {
    int m = blockIdx.x * blockDim.x + threadIdx.x;
    if (m >= N_MOT) return;
    float sum = 0.0f;
    for (int b = 0; b < nb; ++b) sum += partials[(size_t)b * N_MOT + m];
    float v = 0.9f * mem[m] + 20.0f * sum;
    out[m] = (v > 1.0f) ? 1.0f : 0.0f;
}

// --- fallback (tiny workspace): device-atomic scatter --------------------
__global__ void lif_kernel(const float* __restrict__ inp,
                           const float* __restrict__ mem_in,
                           float* __restrict__ spk,
                           float scale, int n) {
    int i = blockIdx.x * blockDim.x + threadIdx.x;
    if (i < n) {
        float m = 0.9f * mem_in[i] + scale * inp[i];
        spk[i] = (m > 1.0f) ? 1.0f : 0.0f;
    }
}

__global__ void scatter_dev(const int* __restrict__ pre,
                            const int* __restrict__ post,
                            const float* __restrict__ w,
                            const float* __restrict__ spikes,
                            float* __restrict__ out,
                            float scale, int n_edges) {
    int e = blockIdx.x * blockDim.x + threadIdx.x;
    if (e >= n_edges) return;
    float s = spikes[pre[e]];
    if (s != 0.0f) atomicAdd(&out[post[e]], scale * w[e] * s);
}

__global__ void lif_hidden_direct(const float* __restrict__ hid_in,
                                  const float* __restrict__ mem,
                                  float* __restrict__ spk) {
    int i = blockIdx.x * blockDim.x + threadIdx.x;
    if (i >= N_HID) return;
    float m = 0.9f * mem[i] + 5.0f * hid_in[i];
    spk[i] = (m > 1.0f) ? 1.0f : 0.0f;
}

__global__ void scatter_motor_f(const int* __restrict__ pre,
                                const int* __restrict__ post,
                                const float* __restrict__ w,
                                const float* __restrict__ spikes,
                                float* __restrict__ partials, int n_edges) {
    __shared__ float acc[N_MOT];
    for (int j = threadIdx.x; j < N_MOT; j += blockDim.x) acc[j] = 0.0f;
    __syncthreads();
    for (int e = blockIdx.x * blockDim.x + threadIdx.x; e < n_edges;
         e += gridDim.x * blockDim.x) {
        float s = spikes[pre[e]];
        if (s != 0.0f) atomicAdd(&acc[post[e]], w[e] * s);
    }
    __syncthreads();
    float* out = partials + (size_t)blockIdx.x * N_MOT;
    for (int j = threadIdx.x; j < N_MOT; j += blockDim.x) out[j] = acc[j];
}

extern "C" void kernel_launch(void* const* d_in, const int* in_sizes, int n_in,
                              void* d_out, int out_size, void* d_ws, size_t ws_size,
                              hipStream_t stream) {
    const float* sensory_input = (const float*)d_in[0];
    const float* sensory_mem   = (const float*)d_in[1];
    const float* hidden_mem    = (const float*)d_in[2];
    const float* motor_mem     = (const float*)d_in[3];
    const float* hidden_prev   = (const float*)d_in[4];
    const float* w_sh          = (const float*)d_in[5];
    const float* w_hh          = (const float*)d_in[6];
    const float* w_hm          = (const float*)d_in[7];
    const int*   sh_pre        = (const int*)d_in[8];
    const int*   sh_post       = (const int*)d_in[9];
    const int*   hh_pre        = (const int*)d_in[10];
    const int*   hh_post       = (const int*)d_in[11];
    const int*   hm_pre        = (const int*)d_in[12];
    const int*   hm_post       = (const int*)d_in[13];
    const int e_sh = in_sizes[5];
    const int e_hh = in_sizes[6];
    const int e_hm = in_sizes[7];
    const int B = 256;

    // fast ws layout (floats, offsets even -> uint2-aligned):
    size_t o_cursor = 0;                                 // 32
    size_t o_extra  = 32;                                // N_HID
    size_t o_pairs  = o_extra + N_HID;                   // NBUCKET*CAP*2
    size_t o_part   = o_pairs + (size_t)NBUCKET * CAP * 2;
    size_t o_smask  = o_part + (size_t)NBUCKET * NCOPY * CHUNK;
    size_t o_hmaskp = o_smask + SENS_MW;
    size_t o_hmasks = o_hmaskp + HID_MW;
    size_t o_mpart  = o_hmasks + HID_MW;
    size_t f_need   = o_mpart + (size_t)NB_HM * N_MOT;
    bool fast = (ws_size / sizeof(float)) >= f_need;

    float* ws = (float*)d_ws;
    if (fast) {
        int*      cursors = (int*)(ws + o_cursor);
        float*    extra   = ws + o_extra;
        uint2*    pairs   = (uint2*)(ws + o_pairs);
        float*    part    = ws + o_part;
        unsigned* smask   = (unsigned*)(ws + o_smask);
        unsigned* hmaskp  = (unsigned*)(ws + o_hmaskp);
        unsigned* hmasks  = (unsigned*)(ws + o_hmasks);
        float*    mpart   = ws + o_mpart;

        int nb_sens = (N_SENS + B - 1) / B;                      // 40
        int nb_hidm = (N_HID + B - 1) / B;                       // 1563
        make_masks<<<nb_sens + nb_hidm, B, 0, stream>>>(
            sensory_input, sensory_mem, hidden_prev,
            (uint2*)smask, (uint2*)hmaskp, extra, cursors, nb_sens);

        int nb_sh = (e_sh + 1024 * EPT_SH - 1) / (1024 * EPT_SH);  // 977
        int nb_hh = (e_hh + 1024 * EPT_HH - 1) / (1024 * EPT_HH);  // 1954
        bin_gather<SENS_MW, BUF_SH, EPT_SH><<<nb_sh, 1024, 0, stream>>>(
            sh_pre, sh_post, w_sh, smask, e_sh, 1.0f, pairs, cursors, extra);
        bin_gather<HID_MW, BUF_HH, EPT_HH><<<nb_hh, 1024, 0, stream>>>(
            hh_pre, hh_post, w_hh, hmaskp, e_hh, 0.5f, pairs, cursors, extra);

        accum_bucket<<<NBUCKET * NCOPY, 1024, 0, stream>>>(pairs, cursors, part);
        reduce_lif_hidden_mask<<<(N_HID + B - 1) / B, B, 0, stream>>>(
            part, extra, hidden_mem, (uint2*)hmasks);
        scatter_motor_mask<<<NB_HM, 512, 0, stream>>>(
            hm_pre, hm_post, w_hm, hmasks, mpart, e_hm);
        reduce_lif_motor<<<(N_MOT + B - 1) / B, B, 0, stream>>>(
            mpart, NB_HM, motor_mem, (float*)d_out);
    } else {
        float* hid_in   = ws;
        float* sens_spk = hid_in + N_HID;
        float* hid_spk  = sens_spk + 10016;
        float* mpart    = hid_spk + N_HID;
        hipMemsetAsync(hid_in, 0, (size_t)N_HID * sizeof(float), stream);
        lif_kernel<<<(N_SENS + B - 1) / B, B, 0, stream>>>(
            sensory_input, sensory_mem, sens_spk, 5.0f, N_SENS);
        scatter_dev<<<(e_sh + B - 1) / B, B, 0, stream>>>(
            sh_pre, sh_post, w_sh, sens_spk, hid_in, 1.0f, e_sh);
        scatter_dev<<<(e_hh + B - 1) / B, B, 0, stream>>>(
            hh_pre, hh_post, w_hh, hidden_prev, hid_in, 0.5f, e_hh);
        lif_hidden_direct<<<(N_HID + B - 1) / B, B, 0, stream>>>(
            hid_in, hidden_mem, hid_spk);
        scatter_motor_f<<<NB_HM, B, 0, stream>>>(
            hm_pre, hm_post, w_hm, hid_spk, mpart, e_hm);
        reduce_lif_motor<<<(N_MOT + B - 1) / B, B, 0, stream>>>(
            mpart, NB_HM, motor_mem, (float*)d_out);
    }
}

// Round 4
// 338.204 us; speedup vs baseline: 1.0538x; 1.0538x over previous
//
#include <hip/hip_runtime.h>

// SNN forward, round 10. Round-9 post-mortem: VGPR_Count=16 proves the
// compiler re-fused the phase-batched loop (arrays would need >=24 VGPR)
// -- the intended MLP never existed. Re-accounting showed the real cost:
// 50KB mask staging = ~6.3K mem-instrs/block for only 8192 edges (EPT=8),
// 97MB total staging traffic, dominating the instruction stream.
// Fixes: EPT_HH 8->32 (489 blocks, 1 round, staging/4), per-lane 32-bit
// activity mask + ONE wave scan + ONE LDS atomic per wave (replaces per-j
// ballot/atomic/shfl chains), gathers in per-j loop (coalesced per step).
// EPT_SH 8 (BUF exact, no overflow). Revert round-9 noise: NCOPY=10,
// motor = round-8 LDS-mask version (both measured faster).

#define N_SENS 10000
#define N_HID  400000
#define N_MOT  1000

#define CHUNK_LOG 14
#define CHUNK     (1 << CHUNK_LOG)      // 16384 floats = 64 KB LDS chunk
#define NBUCKET   25                    // ceil(400000 / 16384)
#define CAP       196608                // pairs/bucket (expect ~175K max)
#define NCOPY     10                    // accum blocks per bucket (250 total)

#define SENS_MW   320                   // sens mask words (u32) = 10240 bits
#define HID_MW    12512                 // hid mask words (u32) = 400384 bits

#define EPT_SH    8
#define BUF_SH    8192                  // = 1024*EPT_SH -> cannot overflow
#define EPT_HH    32
#define BUF_HH    2048                  // expect ~1638 actives (10 sigma)

#define NB_HM     64

// --- masks + zero extra/cursors (replaces a memset dispatch) -------------
__global__ void make_masks(const float* __restrict__ sens_in,
                           const float* __restrict__ sens_mem,
                           const float* __restrict__ hid_prev,
                           uint2* __restrict__ smask,
                           uint2* __restrict__ hmask,
                           float* __restrict__ extra,
                           int* __restrict__ cursors, int nb_sens) {
    bool pred = false;
    int i;
    uint2* dst;
    int maxw;
    if ((int)blockIdx.x < nb_sens) {
        if (blockIdx.x == 0 && threadIdx.x < 32) cursors[threadIdx.x] = 0;
        i = blockIdx.x * blockDim.x + threadIdx.x;
        if (i < N_SENS) pred = (0.9f * sens_mem[i] + 5.0f * sens_in[i]) > 1.0f;
        dst = smask; maxw = SENS_MW / 2;
    } else {
        i = (blockIdx.x - nb_sens) * blockDim.x + threadIdx.x;
        if (i < N_HID) { pred = (hid_prev[i] != 0.0f); extra[i] = 0.0f; }
        dst = hmask; maxw = HID_MW / 2;
    }
    unsigned long long b = __ballot(pred);
    if ((threadIdx.x & 63) == 0) {
        int w = i >> 6;
        if (w < maxw) dst[w] = make_uint2((unsigned)b, (unsigned)(b >> 32));
    }
}

// --- single-pass bin: per-lane activity bitmask, one scan/atomic per wave
template <int MW, int BUFCAP, int EPT>
__global__ __launch_bounds__(1024, 8)
void bin_scan(const int* __restrict__ pre, const int* __restrict__ post,
              const float* __restrict__ w, const unsigned* __restrict__ gmask,
              int n_e, float scale,
              uint2* __restrict__ pairs, int* __restrict__ gcursor,
              float* __restrict__ extra) {
    __shared__ unsigned sm[MW];
    __shared__ uint2 buf[BUFCAP];
    __shared__ int h[4][32];
    __shared__ int gb[32];
    __shared__ int lcur[32];
    __shared__ int total;

    const int tid = threadIdx.x;
    const int lane = tid & 63;
    for (int i = tid; i < MW / 4; i += 1024)
        ((uint4*)sm)[i] = ((const uint4*)gmask)[i];
    if (tid < 128) ((int*)h)[tid] = 0;
    if (tid == 0) total = 0;
    __syncthreads();

    const int base = blockIdx.x * (1024 * EPT) + tid;

    // build per-lane activity bitmask (coalesced pre stream + LDS tests)
    unsigned am = 0;
    #pragma unroll
    for (int j = 0; j < EPT; ++j) {
        int e = base + j * 1024;
        if (e < n_e) {
            int pr = pre[e];
            if ((sm[pr >> 5] >> (pr & 31)) & 1u) am |= (1u << j);
        }
    }
    int cnt = __popc(am);

    // wave-wide inclusive scan of per-lane counts (6 shfl steps)
    int inc = cnt;
    #pragma unroll
    for (int d = 1; d < 64; d <<= 1) {
        int n = __shfl_up(inc, d);
        if (lane >= d) inc += n;
    }
    int wtot = __shfl(inc, 63);
    int wbase = 0;
    if (lane == 63 && wtot) wbase = atomicAdd(&total, wtot);  // 1 per wave
    wbase = __shfl(wbase, 63);
    int off = wbase + inc - cnt;           // exclusive offset for this lane

    // gather + write actives; per-j step keeps gathers coalesced
    #pragma unroll
    for (int j = 0; j < EPT; ++j) {
        if ((am >> j) & 1u) {
            int e = base + j * 1024;
            unsigned p = (unsigned)post[e];
            float wv = scale * w[e];
            if (off < BUFCAP) buf[off] = make_uint2(p, __float_as_uint(wv));
            else atomicAdd(&extra[p], wv);   // ~never taken
            ++off;
        }
    }
    __syncthreads();
    int tot = total; if (tot > BUFCAP) tot = BUFCAP;

    // in-LDS histogram (4-way replicated counters)
    int rep = (tid >> 6) & 3;
    for (int k = tid; k < tot; k += 1024)
        atomicAdd(&h[rep][buf[k].x >> CHUNK_LOG], 1);
    __syncthreads();
    if (tid < NBUCKET) {
        int hb = h[0][tid] + h[1][tid] + h[2][tid] + h[3][tid];
        gb[tid] = hb ? atomicAdd(&gcursor[tid], hb) : 0;
        lcur[tid] = 0;
    }
    __syncthreads();

    // flush: bucket-grouped global writes
    for (int k = tid; k < tot; k += 1024) {
        uint2 u = buf[k];
        int b = u.x >> CHUNK_LOG;
        int s = atomicAdd(&lcur[b], 1);
        int pos = gb[b] + s;
        if (pos < CAP)
            pairs[(size_t)b * CAP + pos] =
                make_uint2(u.x & (CHUNK - 1), u.y);
        else
            atomicAdd(&extra[u.x], __uint_as_float(u.y));  // ~never taken
    }
}

// --- Phase B: LDS ds_add accumulation per (bucket, copy) -----------------
__global__ __launch_bounds__(1024, 8)
void accum_bucket(const uint2* __restrict__ pairs,
                  const int* __restrict__ cursors,
                  float* __restrict__ partials) {
    int bucket = blockIdx.x / NCOPY;
    int copy   = blockIdx.x % NCOPY;
    __shared__ float acc[CHUNK];
    for (int i = threadIdx.x; i < CHUNK; i += blockDim.x) acc[i] = 0.0f;
    __syncthreads();

    int count = cursors[bucket];
    if (count > CAP) count = CAP;
    int begin = (int)((long long)count * copy / NCOPY);
    int end   = (int)((long long)count * (copy + 1) / NCOPY);
    const uint2* src = pairs + (size_t)bucket * CAP;
    for (int i = begin + threadIdx.x; i < end; i += blockDim.x) {
        uint2 u = src[i];
        atomicAdd(&acc[u.x], __uint_as_float(u.y));           // LDS atomic
    }
    __syncthreads();
    float* dst = partials + ((size_t)bucket * NCOPY + copy) * CHUNK;
    for (int i = threadIdx.x; i < CHUNK; i += blockDim.x) dst[i] = acc[i];
}

// --- hidden LIF fused with partial merge (+overflow); emits bitmask ------
__global__ void reduce_lif_hidden_mask(const float* __restrict__ partials,
                                       const float* __restrict__ extra,
                                       const float* __restrict__ mem,
                                       uint2* __restrict__ mask) {
    int i = blockIdx.x * blockDim.x + threadIdx.x;
    bool pred = false;
    if (i < N_HID) {
        int b = i >> CHUNK_LOG, local = i & (CHUNK - 1);
        const float* p = partials + (size_t)b * NCOPY * CHUNK + local;
        float sum = extra[i];
        #pragma unroll
        for (int c = 0; c < NCOPY; ++c) sum += p[(size_t)c * CHUNK];
        pred = (0.9f * mem[i] + 5.0f * sum) > 1.0f;
    }
    unsigned long long bal = __ballot(pred);
    if ((threadIdx.x & 63) == 0) {
        int w = i >> 6;
        if (w < HID_MW / 2)
            mask[w] = make_uint2((unsigned)bal, (unsigned)(bal >> 32));
    }
}

// --- motor: LDS accumulator + LDS hid bitmask, per-block partials --------
__global__ __launch_bounds__(1024, 8)
void scatter_motor_mask(const int* __restrict__ pre,
                        const int* __restrict__ post,
                        const float* __restrict__ w,
                        const unsigned* __restrict__ gmask,
                        float* __restrict__ partials, int n_edges) {
    __shared__ float acc[N_MOT];
    __shared__ unsigned sm[HID_MW];
    for (int i = threadIdx.x; i < HID_MW / 4; i += blockDim.x)
        ((uint4*)sm)[i] = ((const uint4*)gmask)[i];
    for (int j = threadIdx.x; j < N_MOT; j += blockDim.x) acc[j] = 0.0f;
    __syncthreads();
    for (int e = blockIdx.x * blockDim.x + threadIdx.x; e < n_edges;
         e += gridDim.x * blockDim.x) {
        int pr = pre[e];
        if ((sm[pr >> 5] >> (pr & 31)) & 1u)
            atomicAdd(&acc[post[e]], w[e]);
    }
    __syncthreads();
    float* out = partials + (size_t)blockIdx.x * N_MOT;
    for (int j = threadIdx.x; j < N_MOT; j += blockDim.x) out[j] = acc[j];
}

__global__ void reduce_lif_motor(const float* __restrict__ partials, int nb,
                                 const float* __restrict__ mem,
                                 float* __restrict__ out) {
    int m = blockIdx.x * blockDim.x + threadIdx.x;
    if (m >= N_MOT) return;
    float sum = 0.0f;
    for (int b = 0; b < nb; ++b) sum += partials[(size_t)b * N_MOT + m];
    float v = 0.9f * mem[m] + 20.0f * sum;
    out[m] = (v > 1.0f) ? 1.0f : 0.0f;
}

// --- fallback (tiny workspace): device-atomic scatter --------------------
__global__ void lif_kernel(const float* __restrict__ inp,
                           const float* __restrict__ mem_in,
                           float* __restrict__ spk,
                           float scale, int n) {
    int i = blockIdx.x * blockDim.x + threadIdx.x;
    if (i < n) {
        float m = 0.9f * mem_in[i] + scale * inp[i];
        spk[i] = (m > 1.0f) ? 1.0f : 0.0f;
    }
}

__global__ void scatter_dev(const int* __restrict__ pre,
                            const int* __restrict__ post,
                            const float* __restrict__ w,
                            const float* __restrict__ spikes,
                            float* __restrict__ out,
                            float scale, int n_edges) {
    int e = blockIdx.x * blockDim.x + threadIdx.x;
    if (e >= n_edges) return;
    float s = spikes[pre[e]];
    if (s != 0.0f) atomicAdd(&out[post[e]], scale * w[e] * s);
}

__global__ void lif_hidden_direct(const float* __restrict__ hid_in,
                                  const float* __restrict__ mem,
                                  float* __restrict__ spk) {
    int i = blockIdx.x * blockDim.x + threadIdx.x;
    if (i >= N_HID) return;
    float m = 0.9f * mem[i] + 5.0f * hid_in[i];
    spk[i] = (m > 1.0f) ? 1.0f : 0.0f;
}

__global__ void scatter_motor_f(const int* __restrict__ pre,
                                const int* __restrict__ post,
                                const float* __restrict__ w,
                                const float* __restrict__ spikes,
                                float* __restrict__ partials, int n_edges) {
    __shared__ float acc[N_MOT];
    for (int j = threadIdx.x; j < N_MOT; j += blockDim.x) acc[j] = 0.0f;
    __syncthreads();
    for (int e = blockIdx.x * blockDim.x + threadIdx.x; e < n_edges;
         e += gridDim.x * blockDim.x) {
        float s = spikes[pre[e]];
        if (s != 0.0f) atomicAdd(&acc[post[e]], w[e] * s);
    }
    __syncthreads();
    float* out = partials + (size_t)blockIdx.x * N_MOT;
    for (int j = threadIdx.x; j < N_MOT; j += blockDim.x) out[j] = acc[j];
}

extern "C" void kernel_launch(void* const* d_in, const int* in_sizes, int n_in,
                              void* d_out, int out_size, void* d_ws, size_t ws_size,
                              hipStream_t stream) {
    const float* sensory_input = (const float*)d_in[0];
    const float* sensory_mem   = (const float*)d_in[1];
    const float* hidden_mem    = (const float*)d_in[2];
    const float* motor_mem     = (const float*)d_in[3];
    const float* hidden_prev   = (const float*)d_in[4];
    const float* w_sh          = (const float*)d_in[5];
    const float* w_hh          = (const float*)d_in[6];
    const float* w_hm          = (const float*)d_in[7];
    const int*   sh_pre        = (const int*)d_in[8];
    const int*   sh_post       = (const int*)d_in[9];
    const int*   hh_pre        = (const int*)d_in[10];
    const int*   hh_post       = (const int*)d_in[11];
    const int*   hm_pre        = (const int*)d_in[12];
    const int*   hm_post       = (const int*)d_in[13];
    const int e_sh = in_sizes[5];
    const int e_hh = in_sizes[6];
    const int e_hm = in_sizes[7];
    const int B = 256;

    // fast ws layout (floats, offsets even -> uint2-aligned):
    size_t o_cursor = 0;                                 // 32
    size_t o_extra  = 32;                                // N_HID
    size_t o_pairs  = o_extra + N_HID;                   // NBUCKET*CAP*2
    size_t o_part   = o_pairs + (size_t)NBUCKET * CAP * 2;
    size_t o_smask  = o_part + (size_t)NBUCKET * NCOPY * CHUNK;
    size_t o_hmaskp = o_smask + SENS_MW;
    size_t o_hmasks = o_hmaskp + HID_MW;
    size_t o_mpart  = o_hmasks + HID_MW;
    size_t f_need   = o_mpart + (size_t)NB_HM * N_MOT;
    bool fast = (ws_size / sizeof(float)) >= f_need;

    float* ws = (float*)d_ws;
    if (fast) {
        int*      cursors = (int*)(ws + o_cursor);
        float*    extra   = ws + o_extra;
        uint2*    pairs   = (uint2*)(ws + o_pairs);
        float*    part    = ws + o_part;
        unsigned* smask   = (unsigned*)(ws + o_smask);
        unsigned* hmaskp  = (unsigned*)(ws + o_hmaskp);
        unsigned* hmasks  = (unsigned*)(ws + o_hmasks);
        float*    mpart   = ws + o_mpart;

        int nb_sens = (N_SENS + B - 1) / B;                      // 40
        int nb_hidm = (N_HID + B - 1) / B;                       // 1563
        make_masks<<<nb_sens + nb_hidm, B, 0, stream>>>(
            sensory_input, sensory_mem, hidden_prev,
            (uint2*)smask, (uint2*)hmaskp, extra, cursors, nb_sens);

        int nb_sh = (e_sh + 1024 * EPT_SH - 1) / (1024 * EPT_SH);  // 489
        int nb_hh = (e_hh + 1024 * EPT_HH - 1) / (1024 * EPT_HH);  // 489
        bin_scan<SENS_MW, BUF_SH, EPT_SH><<<nb_sh, 1024, 0, stream>>>(
            sh_pre, sh_post, w_sh, smask, e_sh, 1.0f, pairs, cursors, extra);
        bin_scan<HID_MW, BUF_HH, EPT_HH><<<nb_hh, 1024, 0, stream>>>(
            hh_pre, hh_post, w_hh, hmaskp, e_hh, 0.5f, pairs, cursors, extra);

        accum_bucket<<<NBUCKET * NCOPY, 1024, 0, stream>>>(pairs, cursors, part);
        reduce_lif_hidden_mask<<<(N_HID + B - 1) / B, B, 0, stream>>>(
            part, extra, hidden_mem, (uint2*)hmasks);
        scatter_motor_mask<<<NB_HM, 1024, 0, stream>>>(
            hm_pre, hm_post, w_hm, hmasks, mpart, e_hm);
        reduce_lif_motor<<<(N_MOT + B - 1) / B, B, 0, stream>>>(
            mpart, NB_HM, motor_mem, (float*)d_out);
    } else {
        float* hid_in   = ws;
        float* sens_spk = hid_in + N_HID;
        float* hid_spk  = sens_spk + 10016;
        float* mpart    = hid_spk + N_HID;
        hipMemsetAsync(hid_in, 0, (size_t)N_HID * sizeof(float), stream);
        lif_kernel<<<(N_SENS + B - 1) / B, B, 0, stream>>>(
            sensory_input, sensory_mem, sens_spk, 5.0f, N_SENS);
        scatter_dev<<<(e_sh + B - 1) / B, B, 0, stream>>>(
            sh_pre, sh_post, w_sh, sens_spk, hid_in, 1.0f, e_sh);
        scatter_dev<<<(e_hh + B - 1) / B, B, 0, stream>>>(
            hh_pre, hh_post, w_hh, hidden_prev, hid_in, 0.5f, e_hh);
        lif_hidden_direct<<<(N_HID + B - 1) / B, B, 0, stream>>>(
            hid_in, hidden_mem, hid_spk);
        scatter_motor_f<<<NB_HM, B, 0, stream>>>(
            hm_pre, hm_post, w_hm, hid_spk, mpart, e_hm);
        reduce_lif_motor<<<(N_MOT + B - 1) / B, B, 0, stream>>>(
            mpart, NB_HM, motor_mem, (float*)d_out);
    }
}

// Round 5
// 326.794 us; speedup vs baseline: 1.0906x; 1.0349x over previous
//
#include <hip/hip_runtime.h>

// SNN forward, round 11. Round-10 post-mortem: VALU 21->10% but dur flat at
// ~84us -- bin is bound by the GATHER PATTERN, not instructions. At 5% hh
// density, 56% of post/w 64B lines contain an active element, so "active-only"
// gathers fetch ~72MB as scattered latency-bound line touches (FETCH 87.7MB
// confirms). Fix: STREAM pre/post/w for all edges as int4/float4 (128MB at
// streaming BW beats 72MB at gather rates), mask only gates compaction.
// Also: merge sh+hh bins into ONE dispatch, parity-interleaved roles so each
// CU co-hosts one sh + one hh block (fits 133KB/160KB LDS); histogram folded
// into compaction (separate buf re-read pass deleted).

#define N_SENS 10000
#define N_HID  400000
#define N_MOT  1000

#define CHUNK_LOG 14
#define CHUNK     (1 << CHUNK_LOG)      // 16384 floats = 64 KB LDS chunk
#define NBUCKET   25                    // ceil(400000 / 16384)
#define CAP       196608                // pairs/bucket (expect ~175K max)
#define NCOPY     10                    // accum blocks per bucket (250 total)

#define SENS_MW   320                   // sens mask words (u32) = 10240 bits
#define HID_MW    12512                 // hid mask words (u32) = 400384 bits

#define G_SH      2                     // int4 groups/thread -> 8192 edges/blk
#define BUF_SH    8192                  // = max actives -> cannot overflow
#define G_HH      8                     // -> 32768 edges/blk
#define BUF_HH    2048                  // expect ~1638 actives (10 sigma)

#define SMEM_BYTES 66816                // max(320*4+8192*8, 12512*4+2048*8)

#define NB_HM     64

// --- masks + zero extra/cursors (replaces a memset dispatch) -------------
__global__ void make_masks(const float* __restrict__ sens_in,
                           const float* __restrict__ sens_mem,
                           const float* __restrict__ hid_prev,
                           uint2* __restrict__ smask,
                           uint2* __restrict__ hmask,
                           float* __restrict__ extra,
                           int* __restrict__ cursors, int nb_sens) {
    bool pred = false;
    int i;
    uint2* dst;
    int maxw;
    if ((int)blockIdx.x < nb_sens) {
        if (blockIdx.x == 0 && threadIdx.x < 32) cursors[threadIdx.x] = 0;
        i = blockIdx.x * blockDim.x + threadIdx.x;
        if (i < N_SENS) pred = (0.9f * sens_mem[i] + 5.0f * sens_in[i]) > 1.0f;
        dst = smask; maxw = SENS_MW / 2;
    } else {
        i = (blockIdx.x - nb_sens) * blockDim.x + threadIdx.x;
        if (i < N_HID) { pred = (hid_prev[i] != 0.0f); extra[i] = 0.0f; }
        dst = hmask; maxw = HID_MW / 2;
    }
    unsigned long long b = __ballot(pred);
    if ((threadIdx.x & 63) == 0) {
        int w = i >> 6;
        if (w < maxw) dst[w] = make_uint2((unsigned)b, (unsigned)(b >> 32));
    }
}

// --- streamed bin body: vec4 streams, ballot-compact, fused histogram ----
template <int G, int BUFCAP>
__device__ __forceinline__
void bin_body(const int* __restrict__ pre, const int* __restrict__ post,
              const float* __restrict__ w, int n_e, float scale,
              const unsigned* sm, uint2* buf, int (*h)[32], int* total,
              float* __restrict__ extra, int blockStart) {
    const int tid = threadIdx.x;
    const int lane = tid & 63;
    const unsigned long long lt = (1ull << lane) - 1ull;
    const int rep = (tid >> 6) & 3;
    const int base4 = (blockStart >> 2) + tid;
    #pragma unroll
    for (int g = 0; g < G; ++g) {
        int e4 = base4 + g * 1024;
        int e0 = e4 << 2;
        int4 pr4 = make_int4(-1, -1, -1, -1);
        int4 po4 = make_int4(0, 0, 0, 0);
        float4 wv4 = make_float4(0.f, 0.f, 0.f, 0.f);
        if (e0 + 3 < n_e) {
            pr4 = ((const int4*)pre)[e4];
            po4 = ((const int4*)post)[e4];
            wv4 = ((const float4*)w)[e4];
        } else if (e0 < n_e) {
            int t[4] = {-1, -1, -1, -1}, q[4] = {0, 0, 0, 0};
            float f[4] = {0.f, 0.f, 0.f, 0.f};
            for (int k = 0; k < 4; ++k) {
                int e = e0 + k;
                if (e < n_e) { t[k] = pre[e]; q[k] = post[e]; f[k] = w[e]; }
            }
            pr4 = make_int4(t[0], t[1], t[2], t[3]);
            po4 = make_int4(q[0], q[1], q[2], q[3]);
            wv4 = make_float4(f[0], f[1], f[2], f[3]);
        }
        int   prk[4] = {pr4.x, pr4.y, pr4.z, pr4.w};
        int   pok[4] = {po4.x, po4.y, po4.z, po4.w};
        float wk[4]  = {wv4.x, wv4.y, wv4.z, wv4.w};
        #pragma unroll
        for (int k = 0; k < 4; ++k) {
            int pr = prk[k];
            bool act = (pr >= 0) && ((sm[pr >> 5] >> (pr & 31)) & 1u);
            unsigned long long m = __ballot(act);
            if (!m) continue;
            int bse = 0;
            if (lane == 0) bse = atomicAdd(total, (int)__popcll(m));
            bse = __shfl(bse, 0);
            if (act) {
                int idx = bse + (int)__popcll(m & lt);
                unsigned p = (unsigned)pok[k];
                float wv = scale * wk[k];
                if (idx < BUFCAP) {
                    buf[idx] = make_uint2(p, __float_as_uint(wv));
                    atomicAdd(&h[rep][p >> CHUNK_LOG], 1);
                } else {
                    atomicAdd(&extra[p], wv);   // ~never taken
                }
            }
        }
    }
}

// --- merged sh+hh bin, parity-interleaved block roles --------------------
__global__ __launch_bounds__(1024, 8)
void bin_stream(const int* __restrict__ sh_pre, const int* __restrict__ sh_post,
                const float* __restrict__ w_sh, const unsigned* __restrict__ smask,
                int e_sh, int nb_sh,
                const int* __restrict__ hh_pre, const int* __restrict__ hh_post,
                const float* __restrict__ w_hh, const unsigned* __restrict__ hmask,
                int e_hh, int nb_hh,
                uint2* __restrict__ pairs, int* __restrict__ gcursor,
                float* __restrict__ extra) {
    __shared__ __align__(16) char smem[SMEM_BYTES];
    __shared__ int h[4][32];
    __shared__ int gb[32];
    __shared__ int lcur[32];
    __shared__ int total;

    const int tid = threadIdx.x;
    const int bid = blockIdx.x;

    // parity interleave so sh and hh blocks co-reside on each CU
    int nmin = (nb_sh < nb_hh) ? nb_sh : nb_hh;
    bool is_sh;
    int idx;
    if (bid < 2 * nmin) { is_sh = ((bid & 1) == 0); idx = bid >> 1; }
    else { is_sh = (nb_sh > nb_hh); idx = bid - 2 * nmin + nmin; }

    const unsigned* gm = is_sh ? smask : hmask;
    const int mw = is_sh ? SENS_MW : HID_MW;
    unsigned* sm = (unsigned*)smem;
    uint2* buf = (uint2*)(smem + (size_t)mw * 4);

    if (tid < 128) ((int*)h)[tid] = 0;
    if (tid == 0) total = 0;
    for (int i = tid; i < mw / 4; i += 1024)
        ((uint4*)sm)[i] = ((const uint4*)gm)[i];
    __syncthreads();

    if (is_sh)
        bin_body<G_SH, BUF_SH>(sh_pre, sh_post, w_sh, e_sh, 1.0f,
                               sm, buf, h, &total, extra, idx * (4096 * G_SH));
    else
        bin_body<G_HH, BUF_HH>(hh_pre, hh_post, w_hh, e_hh, 0.5f,
                               sm, buf, h, &total, extra, idx * (4096 * G_HH));
    __syncthreads();

    int bufcap = is_sh ? BUF_SH : BUF_HH;
    int tot = total; if (tot > bufcap) tot = bufcap;

    if (tid < NBUCKET) {
        int hb = h[0][tid] + h[1][tid] + h[2][tid] + h[3][tid];
        gb[tid] = hb ? atomicAdd(&gcursor[tid], hb) : 0;
        lcur[tid] = 0;
    }
    __syncthreads();

    for (int k = tid; k < tot; k += 1024) {
        uint2 u = buf[k];
        int b = u.x >> CHUNK_LOG;
        int s = atomicAdd(&lcur[b], 1);
        int pos = gb[b] + s;
        if (pos < CAP)
            pairs[(size_t)b * CAP + pos] =
                make_uint2(u.x & (CHUNK - 1), u.y);
        else
            atomicAdd(&extra[u.x], __uint_as_float(u.y));  // ~never taken
    }
}

// --- Phase B: LDS ds_add accumulation per (bucket, copy) -----------------
__global__ __launch_bounds__(1024, 8)
void accum_bucket(const uint2* __restrict__ pairs,
                  const int* __restrict__ cursors,
                  float* __restrict__ partials) {
    int bucket = blockIdx.x / NCOPY;
    int copy   = blockIdx.x % NCOPY;
    __shared__ float acc[CHUNK];
    for (int i = threadIdx.x; i < CHUNK; i += blockDim.x) acc[i] = 0.0f;
    __syncthreads();

    int count = cursors[bucket];
    if (count > CAP) count = CAP;
    int begin = (int)((long long)count * copy / NCOPY);
    int end   = (int)((long long)count * (copy + 1) / NCOPY);
    const uint2* src = pairs + (size_t)bucket * CAP;
    for (int i = begin + threadIdx.x; i < end; i += blockDim.x) {
        uint2 u = src[i];
        atomicAdd(&acc[u.x], __uint_as_float(u.y));           // LDS atomic
    }
    __syncthreads();
    float* dst = partials + ((size_t)bucket * NCOPY + copy) * CHUNK;
    for (int i = threadIdx.x; i < CHUNK; i += blockDim.x) dst[i] = acc[i];
}

// --- hidden LIF fused with partial merge (+overflow); emits bitmask ------
__global__ void reduce_lif_hidden_mask(const float* __restrict__ partials,
                                       const float* __restrict__ extra,
                                       const float* __restrict__ mem,
                                       uint2* __restrict__ mask) {
    int i = blockIdx.x * blockDim.x + threadIdx.x;
    bool pred = false;
    if (i < N_HID) {
        int b = i >> CHUNK_LOG, local = i & (CHUNK - 1);
        const float* p = partials + (size_t)b * NCOPY * CHUNK + local;
        float sum = extra[i];
        #pragma unroll
        for (int c = 0; c < NCOPY; ++c) sum += p[(size_t)c * CHUNK];
        pred = (0.9f * mem[i] + 5.0f * sum) > 1.0f;
    }
    unsigned long long bal = __ballot(pred);
    if ((threadIdx.x & 63) == 0) {
        int w = i >> 6;
        if (w < HID_MW / 2)
            mask[w] = make_uint2((unsigned)bal, (unsigned)(bal >> 32));
    }
}

// --- motor: LDS accumulator + LDS hid bitmask, per-block partials --------
__global__ __launch_bounds__(1024, 8)
void scatter_motor_mask(const int* __restrict__ pre,
                        const int* __restrict__ post,
                        const float* __restrict__ w,
                        const unsigned* __restrict__ gmask,
                        float* __restrict__ partials, int n_edges) {
    __shared__ float acc[N_MOT];
    __shared__ unsigned sm[HID_MW];
    for (int i = threadIdx.x; i < HID_MW / 4; i += blockDim.x)
        ((uint4*)sm)[i] = ((const uint4*)gmask)[i];
    for (int j = threadIdx.x; j < N_MOT; j += blockDim.x) acc[j] = 0.0f;
    __syncthreads();
    for (int e = blockIdx.x * blockDim.x + threadIdx.x; e < n_edges;
         e += gridDim.x * blockDim.x) {
        int pr = pre[e];
        if ((sm[pr >> 5] >> (pr & 31)) & 1u)
            atomicAdd(&acc[post[e]], w[e]);
    }
    __syncthreads();
    float* out = partials + (size_t)blockIdx.x * N_MOT;
    for (int j = threadIdx.x; j < N_MOT; j += blockDim.x) out[j] = acc[j];
}

__global__ void reduce_lif_motor(const float* __restrict__ partials, int nb,
                                 const float* __restrict__ mem,
                                 float* __restrict__ out) {
    int m = blockIdx.x * blockDim.x + threadIdx.x;
    if (m >= N_MOT) return;
    float sum = 0.0f;
    for (int b = 0; b < nb; ++b) sum += partials[(size_t)b * N_MOT + m];
    float v = 0.9f * mem[m] + 20.0f * sum;
    out[m] = (v > 1.0f) ? 1.0f : 0.0f;
}

// --- fallback (tiny workspace): device-atomic scatter --------------------
__global__ void lif_kernel(const float* __restrict__ inp,
                           const float* __restrict__ mem_in,
                           float* __restrict__ spk,
                           float scale, int n) {
    int i = blockIdx.x * blockDim.x + threadIdx.x;
    if (i < n) {
        float m = 0.9f * mem_in[i] + scale * inp[i];
        spk[i] = (m > 1.0f) ? 1.0f : 0.0f;
    }
}

__global__ void scatter_dev(const int* __restrict__ pre,
                            const int* __restrict__ post,
                            const float* __restrict__ w,
                            const float* __restrict__ spikes,
                            float* __restrict__ out,
                            float scale, int n_edges) {
    int e = blockIdx.x * blockDim.x + threadIdx.x;
    if (e >= n_edges) return;
    float s = spikes[pre[e]];
    if (s != 0.0f) atomicAdd(&out[post[e]], scale * w[e] * s);
}

__global__ void lif_hidden_direct(const float* __restrict__ hid_in,
                                  const float* __restrict__ mem,
                                  float* __restrict__ spk) {
    int i = blockIdx.x * blockDim.x + threadIdx.x;
    if (i >= N_HID) return;
    float m = 0.9f * mem[i] + 5.0f * hid_in[i];
    spk[i] = (m > 1.0f) ? 1.0f : 0.0f;
}

__global__ void scatter_motor_f(const int* __restrict__ pre,
                                const int* __restrict__ post,
                                const float* __restrict__ w,
                                const float* __restrict__ spikes,
                                float* __restrict__ partials, int n_edges) {
    __shared__ float acc[N_MOT];
    for (int j = threadIdx.x; j < N_MOT; j += blockDim.x) acc[j] = 0.0f;
    __syncthreads();
    for (int e = blockIdx.x * blockDim.x + threadIdx.x; e < n_edges;
         e += gridDim.x * blockDim.x) {
        float s = spikes[pre[e]];
        if (s != 0.0f) atomicAdd(&acc[post[e]], w[e] * s);
    }
    __syncthreads();
    float* out = partials + (size_t)blockIdx.x * N_MOT;
    for (int j = threadIdx.x; j < N_MOT; j += blockDim.x) out[j] = acc[j];
}

extern "C" void kernel_launch(void* const* d_in, const int* in_sizes, int n_in,
                              void* d_out, int out_size, void* d_ws, size_t ws_size,
                              hipStream_t stream) {
    const float* sensory_input = (const float*)d_in[0];
    const float* sensory_mem   = (const float*)d_in[1];
    const float* hidden_mem    = (const float*)d_in[2];
    const float* motor_mem     = (const float*)d_in[3];
    const float* hidden_prev   = (const float*)d_in[4];
    const float* w_sh          = (const float*)d_in[5];
    const float* w_hh          = (const float*)d_in[6];
    const float* w_hm          = (const float*)d_in[7];
    const int*   sh_pre        = (const int*)d_in[8];
    const int*   sh_post       = (const int*)d_in[9];
    const int*   hh_pre        = (const int*)d_in[10];
    const int*   hh_post       = (const int*)d_in[11];
    const int*   hm_pre        = (const int*)d_in[12];
    const int*   hm_post       = (const int*)d_in[13];
    const int e_sh = in_sizes[5];
    const int e_hh = in_sizes[6];
    const int e_hm = in_sizes[7];
    const int B = 256;

    // fast ws layout (floats, offsets even -> uint2/uint4-aligned):
    size_t o_cursor = 0;                                 // 32
    size_t o_extra  = 32;                                // N_HID
    size_t o_pairs  = o_extra + N_HID;                   // NBUCKET*CAP*2
    size_t o_part   = o_pairs + (size_t)NBUCKET * CAP * 2;
    size_t o_smask  = o_part + (size_t)NBUCKET * NCOPY * CHUNK;
    size_t o_hmaskp = o_smask + SENS_MW;
    size_t o_hmasks = o_hmaskp + HID_MW;
    size_t o_mpart  = o_hmasks + HID_MW;
    size_t f_need   = o_mpart + (size_t)NB_HM * N_MOT;
    bool fast = (ws_size / sizeof(float)) >= f_need;

    float* ws = (float*)d_ws;
    if (fast) {
        int*      cursors = (int*)(ws + o_cursor);
        float*    extra   = ws + o_extra;
        uint2*    pairs   = (uint2*)(ws + o_pairs);
        float*    part    = ws + o_part;
        unsigned* smask   = (unsigned*)(ws + o_smask);
        unsigned* hmaskp  = (unsigned*)(ws + o_hmaskp);
        unsigned* hmasks  = (unsigned*)(ws + o_hmasks);
        float*    mpart   = ws + o_mpart;

        int nb_sens = (N_SENS + B - 1) / B;                      // 40
        int nb_hidm = (N_HID + B - 1) / B;                       // 1563
        make_masks<<<nb_sens + nb_hidm, B, 0, stream>>>(
            sensory_input, sensory_mem, hidden_prev,
            (uint2*)smask, (uint2*)hmaskp, extra, cursors, nb_sens);

        int nb_sh = (e_sh + 4096 * G_SH - 1) / (4096 * G_SH);    // 489
        int nb_hh = (e_hh + 4096 * G_HH - 1) / (4096 * G_HH);    // 489
        bin_stream<<<nb_sh + nb_hh, 1024, 0, stream>>>(
            sh_pre, sh_post, w_sh, smask, e_sh, nb_sh,
            hh_pre, hh_post, w_hh, hmaskp, e_hh, nb_hh,
            pairs, cursors, extra);

        accum_bucket<<<NBUCKET * NCOPY, 1024, 0, stream>>>(pairs, cursors, part);
        reduce_lif_hidden_mask<<<(N_HID + B - 1) / B, B, 0, stream>>>(
            part, extra, hidden_mem, (uint2*)hmasks);
        scatter_motor_mask<<<NB_HM, 1024, 0, stream>>>(
            hm_pre, hm_post, w_hm, hmasks, mpart, e_hm);
        reduce_lif_motor<<<(N_MOT + B - 1) / B, B, 0, stream>>>(
            mpart, NB_HM, motor_mem, (float*)d_out);
    } else {
        float* hid_in   = ws;
        float* sens_spk = hid_in + N_HID;
        float* hid_spk  = sens_spk + 10016;
        float* mpart    = hid_spk + N_HID;
        hipMemsetAsync(hid_in, 0, (size_t)N_HID * sizeof(float), stream);
        lif_kernel<<<(N_SENS + B - 1) / B, B, 0, stream>>>(
            sensory_input, sensory_mem, sens_spk, 5.0f, N_SENS);
        scatter_dev<<<(e_sh + B - 1) / B, B, 0, stream>>>(
            sh_pre, sh_post, w_sh, sens_spk, hid_in, 1.0f, e_sh);
        scatter_dev<<<(e_hh + B - 1) / B, B, 0, stream>>>(
            hh_pre, hh_post, w_hh, hidden_prev, hid_in, 0.5f, e_hh);
        lif_hidden_direct<<<(N_HID + B - 1) / B, B, 0, stream>>>(
            hid_in, hidden_mem, hid_spk);
        scatter_motor_f<<<NB_HM, B, 0, stream>>>(
            hm_pre, hm_post, w_hm, hid_spk, mpart, e_hm);
        reduce_lif_motor<<<(N_MOT + B - 1) / B, B, 0, stream>>>(
            mpart, NB_HM, motor_mem, (float*)d_out);
    }
}